// Round 1
// baseline (1488.388 us; speedup 1.0000x reference)
//
#include <hip/hip_runtime.h>
#include <math.h>

#define B_   16
#define M_   8
#define T_   250
#define L_   1024
#define NPAIR 28
#define NLAGS 64
#define EPSV 1e-8f

// np.triu_indices(8, k=1)
__constant__ int c_i1[NPAIR] = {0,0,0,0,0,0,0,1,1,1,1,1,1,2,2,2,2,2,3,3,3,3,4,4,4,5,5,6};
__constant__ int c_i2[NPAIR] = {1,2,3,4,5,6,7,2,3,4,5,6,7,3,4,5,6,7,4,5,6,7,5,6,7,6,7,7};

// One block per (b, t). 512 threads.
// Phase 1: DIF radix-2 complex FFT (imag=0) of each of the 8 channel rows,
//          bit-reversed copy-out of bins 0..512 into s_spec.
// Phase 2: thread = (pair p, lag-group lg): computes PHAT-normalized cross
//          spectrum per bin and accumulates 4 lags via unit-rotor recurrence.
__global__ __launch_bounds__(512) void gcc_phat_kernel(const float* __restrict__ x,
                                                       float* __restrict__ out) {
    __shared__ float2 s_buf[L_];          // 8 KB FFT working buffer
    __shared__ float2 s_spec[M_ * 513];   // 32.8 KB spectra (bins 0..512)
    __shared__ float2 s_lut[512];         // 4 KB  e^{-2*pi*i*j/1024}

    const int tid = threadIdx.x;
    const int t  = blockIdx.x;
    const int b  = blockIdx.y;

    // Build forward-FFT twiddle LUT
    {
        float ang = (float)tid * (-6.283185307179586f / 1024.0f);
        float sv, cv;
        sincosf(ang, &sv, &cv);
        s_lut[tid] = make_float2(cv, sv);
    }
    __syncthreads();

    // ---- Phase 1: FFT all 8 channels ----
    for (int m = 0; m < M_; ++m) {
        const float* xr = x + (size_t)(((b * M_ + m) * T_ + t)) * L_;
        for (int i = tid; i < L_; i += 512)
            s_buf[i] = make_float2(xr[i], 0.0f);
        __syncthreads();

        for (int st = 9; st >= 0; --st) {
            const int half = 1 << st;
            const int g    = tid >> st;
            const int pos  = tid & (half - 1);
            const int i0   = (g << (st + 1)) + pos;
            const int i1   = i0 + half;
            float2 a  = s_buf[i0];
            float2 bb = s_buf[i1];
            float2 w  = s_lut[pos << (9 - st)];
            float2 d  = make_float2(a.x - bb.x, a.y - bb.y);
            s_buf[i0] = make_float2(a.x + bb.x, a.y + bb.y);
            s_buf[i1] = make_float2(d.x * w.x - d.y * w.y,
                                    d.x * w.y + d.y * w.x);
            __syncthreads();
        }
        // DIF output is bit-reversed; copy bins 0..512 in natural order
        for (int k = tid; k < 513; k += 512) {
            int rk = (int)(__brev((unsigned)k) >> 22);
            s_spec[m * 513 + k] = s_buf[rk];
        }
        __syncthreads();
    }

    // ---- Phase 2: PHAT-normalized cross spectrum + 64-lag inverse transform ----
    if (tid < NPAIR * 16) {
        const int p  = tid >> 4;      // pair index 0..27
        const int lg = tid & 15;      // lag sub-index
        const float2* X1 = s_spec + c_i1[p] * 513;
        const float2* X2 = s_spec + c_i2[p] * 513;

        float cs[4], sn[4], cr[4], sr[4], acc[4];
#pragma unroll
        for (int j = 0; j < 4; ++j) {
            const int n = lg + 16 * j - 32;   // lag in [-32, 31]
            float ang = (6.283185307179586f / 1024.0f) * (float)n;
            float sv, cv;
            sincosf(ang, &sv, &cv);
            cr[j] = cv; sr[j] = sv;   // per-k step rotor e^{i*2pi*n/1024}
            cs[j] = cv; sn[j] = sv;   // value at k = 1
            acc[j] = 0.0f;
        }

        for (int k = 1; k < 512; ++k) {
            const float2 a  = X1[k];
            const float2 bb = X2[k];
            float Rr = a.x * bb.x + a.y * bb.y;     // X1 * conj(X2)
            float Ri = a.y * bb.x - a.x * bb.y;
            const float inv = 1.0f / (sqrtf(Rr * Rr + Ri * Ri) + EPSV);
            Rr *= inv; Ri *= inv;
#pragma unroll
            for (int j = 0; j < 4; ++j) {
                acc[j] = fmaf(Rr, cs[j], acc[j]);
                acc[j] = fmaf(-Ri, sn[j], acc[j]);
                const float c2 = cs[j] * cr[j] - sn[j] * sr[j];
                const float s2 = sn[j] * cr[j] + cs[j] * sr[j];
                cs[j] = c2; sn[j] = s2;
            }
        }

        // k = 0 and k = 512 (Nyquist) terms: irfft uses their real parts
        const float2 a0 = X1[0],  b0 = X2[0];
        float Rr0 = a0.x * b0.x + a0.y * b0.y;
        float Ri0 = a0.y * b0.x - a0.x * b0.y;
        const float r0 = Rr0 / (sqrtf(Rr0 * Rr0 + Ri0 * Ri0) + EPSV);

        const float2 aN = X1[512], bN = X2[512];
        float RrN = aN.x * bN.x + aN.y * bN.y;
        float RiN = aN.y * bN.x - aN.x * bN.y;
        const float rN = RrN / (sqrtf(RrN * RrN + RiN * RiN) + EPSV);

        float* orow = out + (size_t)(((b * NPAIR + p) * T_ + t)) * NLAGS;
#pragma unroll
        for (int j = 0; j < 4; ++j) {
            const int n = lg + 16 * j - 32;
            const float sgn = (n & 1) ? -1.0f : 1.0f;
            orow[n + 32] = (r0 + sgn * rN + 2.0f * acc[j]) * (1.0f / 1024.0f);
        }
    }
}

extern "C" void kernel_launch(void* const* d_in, const int* in_sizes, int n_in,
                              void* d_out, int out_size, void* d_ws, size_t ws_size,
                              hipStream_t stream) {
    (void)in_sizes; (void)n_in; (void)d_ws; (void)ws_size; (void)out_size;
    const float* x = (const float*)d_in[0];
    float* out = (float*)d_out;
    dim3 grid(T_, B_);
    dim3 block(512);
    hipLaunchKernelGGL(gcc_phat_kernel, grid, block, 0, stream, x, out);
}

// Round 2
// 422.473 us; speedup vs baseline: 3.5230x; 3.5230x over previous
//
#include <hip/hip_runtime.h>
#include <math.h>

#define B_    16
#define M_    8
#define T_    250
#define L_    1024
#define NPAIR 28
#define NLAGS 64

#define KTOT     1152   // padded K = 2*576 bins
#define CH_BINS  144    // bins per K-chunk
#define CH_K     288    // fp16 elems per K-chunk
#define APITCH   296    // CH_K + 8 pad (bank-conflict-friendly, keeps 16B align)
#define NKT      9      // ktiles (K=32) per chunk
#define NCHUNK   4

typedef _Float16 half8  __attribute__((ext_vector_type(8)));
typedef _Float16 half2t __attribute__((ext_vector_type(2)));
typedef float    floatx4 __attribute__((ext_vector_type(4)));

// Twiddle matrix for the 64-lag inverse transform, [lag n][k], k=2b -> cos, 2b+1 -> -sin
__device__ _Float16 g_Btw[NLAGS * KTOT];

// np.triu_indices(8, k=1)
__constant__ int c_i1[NPAIR] = {0,0,0,0,0,0,0,1,1,1,1,1,1,2,2,2,2,2,3,3,3,3,4,4,4,5,5,6};
__constant__ int c_i2[NPAIR] = {1,2,3,4,5,6,7,2,3,4,5,6,7,3,4,5,6,7,4,5,6,7,5,6,7,6,7,7};

__global__ void init_btw() {
    int idx = blockIdx.x * 256 + threadIdx.x;
    if (idx >= NLAGS * KTOT) return;
    int n   = idx / KTOT;
    int k   = idx - n * KTOT;
    int bin = k >> 1;
    float v = 0.0f;
    if (bin <= 512) {
        float cb  = (bin == 0 || bin == 512) ? 1.0f : 2.0f;
        int   tau = n - 32;
        int   r   = (tau * bin) & 1023;              // exact angle residue
        float ang = (float)r * (6.283185307179586f / 1024.0f);
        float s, c;
        sincosf(ang, &s, &c);
        v = ((k & 1) ? -s : c) * cb * (1.0f / 1024.0f);
    }
    g_Btw[idx] = (_Float16)v;
}

// swizzled FFT buffer addressing: kills the 32-way bank conflict on bit-reversed reads
#define SWZ(i) ((i) + ((i) >> 5))

__global__ __launch_bounds__(512) void gcc_main(const float* __restrict__ x,
                                                float* __restrict__ out) {
    __shared__ float2 s_spec[M_][513];                 // 32832 B, fp32 spectra
    __shared__ float2 s_lut[512];                      //  4096 B
    __shared__ union {
        float2   buf[SWZ(1023) + 1];                   //  8440 B (phase 1)
        _Float16 A[32 * APITCH];                       // 18944 B (phases 2/3)
    } su;

    const int tid = threadIdx.x;
    const int t = blockIdx.x, b = blockIdx.y;

    // forward twiddles: e^{-2*pi*i*j/1024}
    {
        float s, c, ang = (float)tid * (-6.283185307179586f / 1024.0f);
        sincosf(ang, &s, &c);
        s_lut[tid] = make_float2(c, s);
    }
    __syncthreads();

    // ---- Phase 1: 4 packed complex FFTs cover 8 real channels ----
    for (int c = 0; c < 4; ++c) {
        const float* xa = x + ((((size_t)b * M_ + 2 * c) * T_ + t) * L_);
        const float* xb = xa + (size_t)T_ * L_;
        su.buf[SWZ(tid)]       = make_float2(xa[tid],       xb[tid]);
        su.buf[SWZ(tid + 512)] = make_float2(xa[tid + 512], xb[tid + 512]);
        __syncthreads();

        for (int st = 9; st >= 0; --st) {
            const int half = 1 << st;
            const int pos  = tid & (half - 1);
            const int i0   = ((tid >> st) << (st + 1)) + pos;
            const int i1   = i0 + half;
            float2 va = su.buf[SWZ(i0)];
            float2 vb = su.buf[SWZ(i1)];
            float2 w  = s_lut[pos << (9 - st)];
            float2 d  = make_float2(va.x - vb.x, va.y - vb.y);
            su.buf[SWZ(i0)] = make_float2(va.x + vb.x, va.y + vb.y);
            su.buf[SWZ(i1)] = make_float2(d.x * w.x - d.y * w.y,
                                          d.x * w.y + d.y * w.x);
            __syncthreads();
        }

        // bit-reversed copy-out + real/real spectrum separation
        {
            const int bb  = tid;
            const int rk  = (int)(__brev((unsigned)bb) >> 22);
            const int rk2 = (int)(__brev((unsigned)((1024 - bb) & 1023)) >> 22);
            float2 Z = su.buf[SWZ(rk)];
            float2 W = su.buf[SWZ(rk2)];
            s_spec[2 * c][bb]     = make_float2(0.5f * (Z.x + W.x), 0.5f * (Z.y - W.y));
            s_spec[2 * c + 1][bb] = make_float2(0.5f * (Z.y + W.y), 0.5f * (W.x - Z.x));
            if (tid == 0) {
                float2 Zn = su.buf[SWZ(1)];            // brev(512) = 1
                s_spec[2 * c][512]     = make_float2(Zn.x, 0.0f);
                s_spec[2 * c + 1][512] = make_float2(Zn.y, 0.0f);
            }
        }
        __syncthreads();
    }

    // ---- Phases 2+3: per K-chunk, normalize cross-spectra into fp16 A, then MFMA ----
    const int lane = tid & 63, wv = tid >> 6;
    const int mt = wv >> 2, nt = wv & 3;               // 2 M-tiles x 4 N-tiles
    const int l15 = lane & 15, quad = lane >> 4;
    const int arow = mt * 16 + l15;
    const int brow = nt * 16 + l15;
    floatx4 acc = {0.0f, 0.0f, 0.0f, 0.0f};

    for (int h = 0; h < NCHUNK; ++h) {
        // fill A[pair][2b]=Rr, [2b+1]=Ri (PHAT-normalized), rows 28..31 and pad bins zero
#pragma unroll 3
        for (int it = 0; it < 9; ++it) {
            int e   = tid + it * 512;
            int p   = e / CH_BINS;
            int bl  = e - p * CH_BINS;
            int bin = h * CH_BINS + bl;
            float rr = 0.0f, ri = 0.0f;
            if (p < NPAIR && bin <= 512) {
                float2 X1 = s_spec[c_i1[p]][bin];
                float2 X2 = s_spec[c_i2[p]][bin];
                rr = X1.x * X2.x + X1.y * X2.y;
                ri = X1.y * X2.x - X1.x * X2.y;
                float m2  = rr * rr + ri * ri;
                float inv = (m2 > 1e-30f) ? rsqrtf(m2) : 0.0f;
                rr *= inv; ri *= inv;
            }
            *(half2t*)&su.A[p * APITCH + 2 * bl] = (half2t){(_Float16)rr, (_Float16)ri};
        }
        __syncthreads();

        const _Float16* Ap = su.A  + arow * APITCH;
        const _Float16* Bp = g_Btw + brow * KTOT + h * CH_K;
#pragma unroll
        for (int kt = 0; kt < NKT; ++kt) {
            half8 af = *(const half8*)(Ap + kt * 32 + quad * 8);
            half8 bf = *(const half8*)(Bp + kt * 32 + quad * 8);
            acc = __builtin_amdgcn_mfma_f32_16x16x32_f16(af, bf, acc, 0, 0, 0);
        }
        __syncthreads();
    }

    // ---- Epilogue: C/D layout col=lane&15, row=quad*4+reg ----
#pragma unroll
    for (int r = 0; r < 4; ++r) {
        int pair = mt * 16 + quad * 4 + r;
        if (pair < NPAIR) {
            out[((((size_t)b * NPAIR + pair) * T_ + t) << 6) + nt * 16 + l15] = acc[r];
        }
    }
}

extern "C" void kernel_launch(void* const* d_in, const int* in_sizes, int n_in,
                              void* d_out, int out_size, void* d_ws, size_t ws_size,
                              hipStream_t stream) {
    (void)in_sizes; (void)n_in; (void)d_ws; (void)ws_size; (void)out_size;
    hipLaunchKernelGGL(init_btw, dim3((NLAGS * KTOT + 255) / 256), dim3(256), 0, stream);
    hipLaunchKernelGGL(gcc_main, dim3(T_, B_), dim3(512), 0, stream,
                       (const float*)d_in[0], (float*)d_out);
}